// Round 9
// baseline (155.169 us; speedup 1.0000x reference)
//
#include <hip/hip_runtime.h>

#define NN 8000
#define FD 256
#define NEG_SLOPE 0.2f
#define BI 64                 // i's per block (4 waves x 16)
#define KT 64                 // j's per step
#define JS 4                  // j chunks: starts 0,2048,4096,6144

typedef __bf16 bf16;
typedef __bf16 bf16x8 __attribute__((ext_vector_type(8)));
typedef float f32x4 __attribute__((ext_vector_type(4)));

// ---------------- K1: H = X @ W^T + b -> Ht (bf16, [f][i]); zeroes outT/lg ----
__global__ __launch_bounds__(256) void k_linear(const float* __restrict__ X,
                                                const float* __restrict__ W,
                                                const float* __restrict__ b,
                                                bf16* __restrict__ Ht,
                                                float* __restrict__ outT,
                                                float* __restrict__ lg) {
    __shared__ float Xs[16][260];
    const int t = threadIdx.x;
    const int i0 = blockIdx.x * 16;
    {   // zero outT (8 MB) + lg
        const int gt = blockIdx.x * 256 + t;          // 128000 threads
        const float4 z4 = {0.f, 0.f, 0.f, 0.f};
        float4* o4 = (float4*)outT;
        #pragma unroll
        for (int k = 0; k < 4; ++k) o4[gt + k * 128000] = z4;
        if (gt < NN) lg[gt] = 0.f;
    }
    #pragma unroll
    for (int r = 0; r < 16; ++r)
        Xs[r][t] = X[(size_t)(i0 + r) * FD + t];
    __syncthreads();
    const int f = t;
    float acc[16];
    const float bf_ = b[f];
    #pragma unroll
    for (int ii = 0; ii < 16; ++ii) acc[ii] = bf_;
    for (int k4 = 0; k4 < FD / 4; ++k4) {
        const float4 w4 = *(const float4*)&W[(size_t)f * FD + k4 * 4];
        #pragma unroll
        for (int ii = 0; ii < 16; ++ii) {
            const float4 x4 = *(const float4*)&Xs[ii][k4 * 4];
            acc[ii] += x4.x * w4.x + x4.y * w4.y + x4.z * w4.z + x4.w * w4.w;
        }
    }
    bf16x8 v0, v1;
    #pragma unroll
    for (int ii = 0; ii < 8; ++ii) { v0[ii] = (bf16)acc[ii]; v1[ii] = (bf16)acc[ii + 8]; }
    *(bf16x8*)&Ht[(size_t)f * NN + i0]     = v0;
    *(bf16x8*)&Ht[(size_t)f * NN + i0 + 8] = v1;
}

// ---------------- K2: hs = H@a_src + a_b, hd = H@a_dst ----------------
__global__ __launch_bounds__(256) void k_attn_vec(const bf16* __restrict__ Ht,
                                                  const float* __restrict__ a_src,
                                                  const float* __restrict__ a_dst,
                                                  const float* __restrict__ a_b,
                                                  float* __restrict__ hs,
                                                  float* __restrict__ hd) {
    __shared__ float psh[4][64], pdh[4][64];
    const int t = threadIdx.x;
    const int li = t & 63;
    const int q = t >> 6;
    const int i = blockIdx.x * 64 + li;
    float ps = 0.f, pd = 0.f;
    #pragma unroll 8
    for (int fi = 0; fi < 64; ++fi) {
        const int f = q * 64 + fi;
        const float h = (float)Ht[(size_t)f * NN + i];
        ps += h * a_src[f];
        pd += h * a_dst[f];
    }
    psh[q][li] = ps; pdh[q][li] = pd;
    __syncthreads();
    if (q == 0) {
        ps = psh[0][li] + psh[1][li] + psh[2][li] + psh[3][li];
        pd = pdh[0][li] + pdh[1][li] + pdh[2][li] + pdh[3][li];
        hs[i] = ps + a_b[0];
        hd[i] = pd;
    }
}

__device__ __forceinline__ bf16x8 wgen(int4 alo, int4 ahi, float4 hlo, float4 hhi,
                                       float hsv, float& ls) {
    float w[8]; float e;
    e = hsv + hlo.x; e = e >= 0.f ? e : NEG_SLOPE * e; w[0] = alo.x ? __expf(e) : 0.f;
    e = hsv + hlo.y; e = e >= 0.f ? e : NEG_SLOPE * e; w[1] = alo.y ? __expf(e) : 0.f;
    e = hsv + hlo.z; e = e >= 0.f ? e : NEG_SLOPE * e; w[2] = alo.z ? __expf(e) : 0.f;
    e = hsv + hlo.w; e = e >= 0.f ? e : NEG_SLOPE * e; w[3] = alo.w ? __expf(e) : 0.f;
    e = hsv + hhi.x; e = e >= 0.f ? e : NEG_SLOPE * e; w[4] = ahi.x ? __expf(e) : 0.f;
    e = hsv + hhi.y; e = e >= 0.f ? e : NEG_SLOPE * e; w[5] = ahi.y ? __expf(e) : 0.f;
    e = hsv + hhi.z; e = e >= 0.f ? e : NEG_SLOPE * e; w[6] = ahi.z ? __expf(e) : 0.f;
    e = hsv + hhi.w; e = e >= 0.f ? e : NEG_SLOPE * e; w[7] = ahi.w ? __expf(e) : 0.f;
    ls += ((w[0] + w[1]) + (w[2] + w[3])) + ((w[4] + w[5]) + (w[6] + w[7]));
    bf16x8 r;
    #pragma unroll
    for (int i = 0; i < 8; ++i) r[i] = (bf16)w[i];
    return r;
}

// ---------------- K3: transposed GEMM — weights in the B operand ----------------
// outT[f][i] = sum_j Ht[f][j] * w[i][j].  256 thr (4 waves x 16 i's = 64 i's/block),
// j-split x4. Lane l owns column i = i0+wv*16+(l&15); generates its B-frag
// (8 weights, k=(l>>4)*8+e) IN REGISTER — no weight LDS, no producer barrier.
// A = Ht[0..255][j-tile] staged once/step via global_load_lds (slot-XOR both
// sides, 128B rows -> <=2-way conflicts), double-buffered, 2 barriers/step.
__global__ __launch_bounds__(256, 2) void k_gat(const bf16* __restrict__ Ht,
                                                const int* __restrict__ adj,
                                                const float* __restrict__ hs,
                                                const float* __restrict__ hd,
                                                float* __restrict__ outT,
                                                float* __restrict__ lg) {
    __shared__ __attribute__((aligned(16))) bf16 As[2][FD * KT];   // 2 x 32 KB

    const int t  = threadIdx.x;
    const int l  = t & 63;
    const int wv = t >> 6;
    const int ib = blockIdx.x >> 2;
    const int jb = blockIdx.x & 3;
    const int i0 = ib * BI;
    const int jq0 = jb * 2048;
    const int NS = (jb < 3) ? 32 : 29;     // 32*64=2048; last: 29*64=1856 (sum 8000)

    const int al = l & 15, asl = l >> 4;
    const int i = i0 + wv * 16 + al;
    const float hsv = hs[i];
    const int*   adjp = adj + (size_t)i * NN + jq0 + asl * 8;
    const float* hdp  = hd + jq0 + asl * 8;

    // stage Ht[0..255][j0+s*64 .. +64) -> As[buf], linear dest, source slot-XOR
    auto stage = [&](int s_, int bufi) {
        #pragma unroll
        for (int q = 0; q < 8; ++q) {
            const int idx = q * 256 + t;
            const int row = idx >> 3;                 // f row 0..255
            const int sslot = (idx & 7) ^ (row & 7);  // source 16B-slot
            const bf16* src = Ht + (size_t)row * NN + jq0 + s_ * KT + sslot * 8;
            bf16* dst = &As[bufi][idx * 8];           // byte offset idx*16 (linear)
            __builtin_amdgcn_global_load_lds(
                (const __attribute__((address_space(1))) void*)src,
                (__attribute__((address_space(3))) void*)dst, 16, 0, 0);
        }
    };

    // prologue
    stage(0, 0);
    int4 aj0 = *(const int4*)adjp,        aj1 = *(const int4*)(adjp + 4);
    int4 aj2 = *(const int4*)(adjp + 32), aj3 = *(const int4*)(adjp + 36);
    float4 hc0 = *(const float4*)hdp,        hc1 = *(const float4*)(hdp + 4);
    float4 hc2 = *(const float4*)(hdp + 32), hc3 = *(const float4*)(hdp + 36);

    f32x4 acc[16];
    #pragma unroll
    for (int ff = 0; ff < 16; ++ff) acc[ff] = (f32x4){0.f, 0.f, 0.f, 0.f};
    float lsum = 0.f;

    #pragma unroll 1
    for (int s = 0; s < NS; ++s) {
        const int cur = s & 1;
        int4 na0, na1, na2, na3; float4 nh0, nh1, nh2, nh3;
        if (s + 1 < NS) {
            stage(s + 1, cur ^ 1);
            const int o = (s + 1) * KT;
            na0 = *(const int4*)(adjp + o);      na1 = *(const int4*)(adjp + o + 4);
            na2 = *(const int4*)(adjp + o + 32); na3 = *(const int4*)(adjp + o + 36);
            nh0 = *(const float4*)(hdp + o);      nh1 = *(const float4*)(hdp + o + 4);
            nh2 = *(const float4*)(hdp + o + 32); nh3 = *(const float4*)(hdp + o + 36);
        }

        // in-register B-frags (weights) for kpass 0 and 1
        const bf16x8 b0 = wgen(aj0, aj1, hc0, hc1, hsv, lsum);
        const bf16x8 b1 = wgen(aj2, aj3, hc2, hc3, hsv, lsum);

        // As[cur] (stage(s)) drained: 16 newer ops (stage(s+1)=8, adj=4, hd=4) may fly
        if (s + 1 < NS) asm volatile("s_waitcnt vmcnt(16)" ::: "memory");
        else            asm volatile("s_waitcnt vmcnt(0)" ::: "memory");
        __builtin_amdgcn_s_barrier();

        // 16 f-frags x 2 kpasses; A-frag row f=ff*16+al, slot s8 ^ (al&7)
        {
            const char* Ab = (const char*)&As[cur][0];
            #pragma unroll
            for (int ff = 0; ff < 16; ++ff) {
                const int rb = (ff * 16 + al) * 128;
                const bf16x8 a0 = *(const bf16x8*)(Ab + rb + ((asl ^ (al & 7)) << 4));
                const bf16x8 a1 = *(const bf16x8*)(Ab + rb + (((4 + asl) ^ (al & 7)) << 4));
                acc[ff] = __builtin_amdgcn_mfma_f32_16x16x32_bf16(a0, b0, acc[ff], 0, 0, 0);
                acc[ff] = __builtin_amdgcn_mfma_f32_16x16x32_bf16(a1, b1, acc[ff], 0, 0, 0);
            }
        }
        asm volatile("s_waitcnt lgkmcnt(0)" ::: "memory");
        __builtin_amdgcn_s_barrier();   // all reads of As[cur] done before s+2 stages it

        aj0 = na0; aj1 = na1; aj2 = na2; aj3 = na3;
        hc0 = nh0; hc1 = nh1; hc2 = nh2; hc3 = nh3;
    }

    // column sums: lanes {l, l^16, l^32, l^48} share i
    lsum += __shfl_xor(lsum, 16);
    lsum += __shfl_xor(lsum, 32);
    if (asl == 0) atomicAdd(&lg[i], lsum);

    // outT[f][i], coalesced 64B per 16-lane group; JS contributions per element
    #pragma unroll
    for (int ff = 0; ff < 16; ++ff) {
        #pragma unroll
        for (int g = 0; g < 4; ++g) {
            atomicAdd(&outT[(size_t)(ff * 16 + asl * 4 + g) * NN + i], acc[ff][g]);
        }
    }
}

// ---------------- K4: transpose outT -> out with row-sum divide ----------------
__global__ __launch_bounds__(256) void k_norm(const float* __restrict__ outT,
                                              const float* __restrict__ lg,
                                              float* __restrict__ out) {
    __shared__ float Ts[64][65];
    const int t = threadIdx.x;
    const int tx = t & 63, ty = t >> 6;
    const int ib = blockIdx.x >> 2, fb = blockIdx.x & 3;
    const int i0 = ib * 64, f0 = fb * 64;
    #pragma unroll
    for (int r = 0; r < 16; ++r) {
        const int f = ty * 16 + r;
        Ts[f][tx] = outT[(size_t)(f0 + f) * NN + i0 + tx];
    }
    __syncthreads();
    #pragma unroll
    for (int r = 0; r < 16; ++r) {
        const int irow = ty * 16 + r;
        const float rinv = 1.0f / lg[i0 + irow];
        out[(size_t)(i0 + irow) * FD + f0 + tx] = Ts[tx][irow] * rinv;
    }
}

extern "C" void kernel_launch(void* const* d_in, const int* in_sizes, int n_in,
                              void* d_out, int out_size, void* d_ws, size_t ws_size,
                              hipStream_t stream) {
    const float* X     = (const float*)d_in[0];
    const int*   adj   = (const int*)d_in[1];
    const float* Ww    = (const float*)d_in[2];
    const float* Wb    = (const float*)d_in[3];
    const float* a_src = (const float*)d_in[4];
    const float* a_dst = (const float*)d_in[5];
    const float* a_b   = (const float*)d_in[6];
    float* out = (float*)d_out;

    bf16*  Ht   = (bf16*)d_ws;                                // 4.096 MB
    float* hs   = (float*)((char*)d_ws + (size_t)FD * NN * sizeof(bf16));
    float* hd   = hs + NN;
    float* lg   = hd + NN;
    float* outT = lg + NN;                                    // 8.192 MB

    k_linear<<<NN / 16, 256, 0, stream>>>(X, Ww, Wb, Ht, outT, lg);
    k_attn_vec<<<NN / 64, 256, 0, stream>>>(Ht, a_src, a_dst, a_b, hs, hd);
    k_gat<<<(NN / BI) * JS, 256, 0, stream>>>(Ht, adj, hs, hd, outT, lg);
    k_norm<<<(NN / 64) * (FD / 64), 256, 0, stream>>>(outT, lg, out);
}